// Round 5
// baseline (201.728 us; speedup 1.0000x reference)
//
#include <hip/hip_runtime.h>

// Problem constants (fixed by reference)
#define NPTS  8192
#define GXD   334
#define GYD   334
#define GZD   2
#define BATCH 2
#define NV    (BATCH * GZD * GYD * GXD)   // 446224 voxel cells
#define NVP   446464                       // padded to multiple of 256
#define KADJ  50
#define TROUNDS 24

#define GBLK  512     // gather blocks
#define GTHR  1024    // 512*1024 = 8192 waves -> exactly one wave per point

__device__ __forceinline__ void voxel_coords(float x, float y, float z,
                                             int& cx, int& cy, int& cz) {
    // Mirror ref exactly: floor((p - PC_MIN) / VOXEL), clip after cast.
    cx = (int)floorf((x - (-50.0f)) / 0.3f);
    cy = (int)floorf((y - (-50.0f)) / 0.3f);
    cz = (int)floorf((z - (-5.0f))  / 6.0f);
    cx = min(max(cx, 0), GXD - 1);
    cy = min(max(cy, 0), GYD - 1);
    cz = min(max(cz, 0), GZD - 1);
}

// Phase 1: direct-addressed voxel accumulate (no hash, no CAS).
// rep encoding: atomicMax of (NPTS-1-i) over zero-init -> decode NPTS-1-v = min index.
__global__ void k_accum(const float* __restrict__ pts, const int* __restrict__ bidx,
                        float* cnt, float* sx, float* sy, float* sz, int* rep) {
    int i = blockIdx.x * blockDim.x + threadIdx.x;
    if (i >= NPTS) return;
    float x = pts[3 * i + 0], y = pts[3 * i + 1], z = pts[3 * i + 2];
    int cx, cy, cz;
    voxel_coords(x, y, z, cx, cy, cz);
    int b = bidx[i];
    int vid = ((b * GZD + cz) * GYD + cy) * GXD + cx;
    atomicAdd(&cnt[vid], 1.0f);
    atomicAdd(&sx[vid], x);
    atomicAdd(&sy[vid], y);
    atomicAdd(&sz[vid], z);
    atomicMax(&rep[vid], NPTS - 1 - i);
}

// Phase 2+3: one wave per point gathers adjacency (lane = window cell);
// the LAST block to finish runs the connected-components phase in LDS.
__global__ void __launch_bounds__(GTHR) k_gather_cc(
        const float* __restrict__ pts, const int* __restrict__ bidx,
        const float* __restrict__ cnt, const float* __restrict__ sx,
        const float* __restrict__ sy, const float* __restrict__ sz,
        const int* __restrict__ rep,
        int* __restrict__ deg, int* __restrict__ adj, int* done,
        float* __restrict__ out) {
    int tid  = blockIdx.x * GTHR + threadIdx.x;
    int w    = tid >> 6;          // 0..8191: point index
    int lane = tid & 63;
    int i    = w;

    // wave-uniform loads
    float x = pts[3 * i + 0], y = pts[3 * i + 1], z = pts[3 * i + 2];
    int cx, cy, cz;
    voxel_coords(x, y, z, cx, cy, cz);
    int b   = bidx[i];
    int vid = ((b * GZD + cz) * GYD + cy) * GXD + cx;

    // lane < 50: this lane's window cell (zz, dy, dx)
    bool  occ = false;
    float ncn = 1.0f, nxc = 0.0f, nyc = 0.0f;
    int   nrep = 0;
    if (lane < KADJ) {
        int zz  = lane / 25;
        int rem = lane % 25;
        int dy  = rem / 5 - 2;
        int dx  = rem % 5 - 2;
        int ny = cy + dy, nx = cx + dx;
        if (ny >= 0 && ny < GYD && nx >= 0 && nx < GXD) {
            int nvid = ((b * GZD + zz) * GYD + ny) * GXD + nx;
            float c = cnt[nvid];
            if (c > 0.0f) {
                occ  = true;
                ncn  = fmaxf(c, 1.0f);          // ref: sums / maximum(cnt,1)
                nxc  = sx[nvid] / ncn;
                nyc  = sy[nvid] / ncn;
                nrep = NPTS - 1 - rep[nvid];    // decode min point index
            }
        }
    }

    // own voxel center broadcast from the (dx=0,dy=0,zz=cz) lane
    int lane_own = cz * 25 + 12;
    float cxf    = __shfl(nxc, lane_own);
    float cyf    = __shfl(nyc, lane_own);
    float cn_own = __shfl(ncn, lane_own);

    bool pred = false;
    if (occ) {
        float ddx = cxf - nxc;
        float ddy = cyf - nyc;
        // separate roundings like ref (no FMA contraction)
        float sq = __fadd_rn(__fmul_rn(ddx, ddx), __fmul_rn(ddy, ddy));
        pred = (sqrtf(sq) < 0.6f);
    }
    unsigned long long mask = __ballot(pred);
    if (pred) {
        int rank = __popcll(mask & ((1ull << lane) - 1ull));
        adj[i * KADJ + rank] = nrep;
    }
    if (lane == 0) {
        deg[i] = __popcll(mask);
        // float32 outputs: cluster_inds interleaved [b,c], valid, cpp
        out[2 * i]                = (float)b;
        out[2 * NPTS + i]         = 1.0f;          // cnt >= MIN_POINTS=1 always
        out[3 * NPTS + 3 * i + 0] = cxf;
        out[3 * NPTS + 3 * i + 1] = cyf;
        out[3 * NPTS + 3 * i + 2] = sz[vid] / cn_own;
    }

    // ---- last-block-runs-CC handshake ----
    __shared__ int isLast;
    __threadfence();                       // publish adj/deg/out stores (release)
    __syncthreads();
    if (threadIdx.x == 0)
        isLast = (atomicAdd(done, 1) == GBLK - 1);
    __syncthreads();
    if (!isLast) return;
    __threadfence();                       // acquire all blocks' stores

    // ---- CC: labels in LDS, min-label propagation + hook + pointer jumping,
    // early exit at fixed point (== component min; labels monotone-decreasing
    // from identity, always an index within the component).
    __shared__ int l[NPTS];
    __shared__ int changed;
    int t = threadIdx.x;
    for (int j = t; j < NPTS; j += GTHR) l[j] = j;
    __syncthreads();
    for (int r = 0; r < TROUNDS; r++) {
        __syncthreads();
        if (t == 0) changed = 0;
        __syncthreads();
        for (int j = t; j < NPTS; j += GTHR) {
            int old = l[j];
            int m = old;
            int d = deg[j];
            const int* a = &adj[j * KADJ];
            for (int e = 0; e < d; e++) {
                int lj = l[a[e]];
                if (lj < m) m = lj;
            }
            if (m < old) {
                atomicMin(&l[j], m);
                atomicMin(&l[old], m);     // hook at old root
                changed = 1;
            }
        }
        __syncthreads();
        for (int jp = 0; jp < 2; jp++) {   // pointer jumping x2
            for (int j = t; j < NPTS; j += GTHR) {
                int a2 = l[j];
                int b2 = l[a2];
                if (b2 < a2) { l[j] = b2; changed = 1; }
            }
            __syncthreads();
        }
        if (!changed) break;
    }
    for (int j = t; j < NPTS; j += GTHR)
        out[2 * j + 1] = (float)l[j];
}

extern "C" void kernel_launch(void* const* d_in, const int* in_sizes, int n_in,
                              void* d_out, int out_size, void* d_ws, size_t ws_size,
                              hipStream_t stream) {
    const float* pts  = (const float*)d_in[0];
    const int*   bidx = (const int*)d_in[1];
    float* out = (float*)d_out;

    char* w = (char*)d_ws;
    float* cnt  = (float*)(w + 0L * NVP * 4);
    float* sx   = (float*)(w + 1L * NVP * 4);
    float* sy   = (float*)(w + 2L * NVP * 4);
    float* sz   = (float*)(w + 3L * NVP * 4);
    int*   rep  = (int*)  (w + 4L * NVP * 4);
    int*   done = (int*)  (w + 5L * NVP * 4);            // inside memset region
    int*   adj  = (int*)  (w + 5L * NVP * 4 + 256);      // 8192*50 ints
    int*   deg  = (int*)  (w + 5L * NVP * 4 + 256 + (long)NPTS * KADJ * 4);
    // total ws use ~10.6 MB (ws is ~256 MB per harness poison traffic)

    // Single zero-fill initializes cnt/sx/sy/sz/rep AND the done counter.
    hipMemsetAsync(w, 0, 5L * NVP * 4 + 256, stream);

    hipLaunchKernelGGL(k_accum, dim3(NPTS / 256), dim3(256), 0, stream,
                       pts, bidx, cnt, sx, sy, sz, rep);
    hipLaunchKernelGGL(k_gather_cc, dim3(GBLK), dim3(GTHR), 0, stream,
                       pts, bidx, cnt, sx, sy, sz, rep, deg, adj, done, out);
}

// Round 6
// 24.722 us; speedup vs baseline: 8.1600x; 8.1600x over previous
//
#include <hip/hip_runtime.h>

// Problem constants (fixed by reference)
#define NPTS  8192
#define GXD   334
#define GYD   334
#define GZD   2
#define BATCH 2
#define NV    (BATCH * GZD * GYD * GXD)   // 446224 voxel cells
#define NVP   446464                       // padded to multiple of 256
#define KADJ  50

__device__ __forceinline__ void voxel_coords(float x, float y, float z,
                                             int& cx, int& cy, int& cz) {
    // Mirror ref exactly: floor((p - PC_MIN) / VOXEL), clip after cast.
    cx = (int)floorf((x - (-50.0f)) / 0.3f);
    cy = (int)floorf((y - (-50.0f)) / 0.3f);
    cz = (int)floorf((z - (-5.0f))  / 6.0f);
    cx = min(max(cx, 0), GXD - 1);
    cy = min(max(cy, 0), GYD - 1);
    cz = min(max(cz, 0), GZD - 1);
}

// ECL-CC-style find with path halving. Plain reads/writes are safe: every
// parent value is a smaller member of the same component (monotone chains);
// stale reads at worst cause a CAS retry in unite().
__device__ __forceinline__ int rep_find(int* parent, int v) {
    int curr = parent[v];
    if (curr != v) {
        int prev = v, next;
        while (curr > (next = parent[curr])) {
            parent[prev] = next;   // halving hint (benign race)
            prev = curr;
            curr = next;
        }
    }
    return curr;
}

// Attach larger root under smaller value; CAS validates against races.
__device__ __forceinline__ void unite(int* parent, int u, int v) {
    int ru = rep_find(parent, u);
    int rv = rep_find(parent, v);
    while (ru != rv) {
        if (ru < rv) { int t = ru; ru = rv; rv = t; }   // ru = larger
        int prev = atomicCAS(&parent[ru], ru, rv);
        if (prev == ru) return;                          // linked
        ru = rep_find(parent, prev);                     // fresh info from CAS
        rv = rep_find(parent, rv);
    }
}

// Phase 1: direct-addressed voxel accumulate + parent init.
// rep encoding: atomicMax(NPTS-1-i) over zero-init -> decode NPTS-1-v = min idx.
__global__ void k_accum(const float* __restrict__ pts, const int* __restrict__ bidx,
                        float* cnt, float* sx, float* sy, float* sz, int* rep,
                        int* parent) {
    int i = blockIdx.x * blockDim.x + threadIdx.x;
    if (i >= NPTS) return;
    parent[i] = i;
    float x = pts[3 * i + 0], y = pts[3 * i + 1], z = pts[3 * i + 2];
    int cx, cy, cz;
    voxel_coords(x, y, z, cx, cy, cz);
    int b = bidx[i];
    int vid = ((b * GZD + cz) * GYD + cy) * GXD + cx;
    atomicAdd(&cnt[vid], 1.0f);
    atomicAdd(&sx[vid], x);
    atomicAdd(&sy[vid], y);
    atomicAdd(&sz[vid], z);
    atomicMax(&rep[vid], NPTS - 1 - i);
}

// Phase 2: one 64-lane wave per point; lane < 50 owns window cell (zz,dy,dx).
// Passing lanes union the point with the neighbor voxel's representative.
__global__ void __launch_bounds__(256) k_gather_union(
        const float* __restrict__ pts, const int* __restrict__ bidx,
        const float* __restrict__ cnt, const float* __restrict__ sx,
        const float* __restrict__ sy, const float* __restrict__ sz,
        const int* __restrict__ rep, int* parent,
        float* __restrict__ out) {
    int tid  = blockIdx.x * 256 + threadIdx.x;
    int i    = tid >> 6;          // point index (2048 blocks * 4 waves = 8192)
    int lane = tid & 63;

    // wave-uniform loads
    float x = pts[3 * i + 0], y = pts[3 * i + 1], z = pts[3 * i + 2];
    int cx, cy, cz;
    voxel_coords(x, y, z, cx, cy, cz);
    int b   = bidx[i];
    int vid = ((b * GZD + cz) * GYD + cy) * GXD + cx;

    bool  occ = false;
    float ncn = 1.0f, nxc = 0.0f, nyc = 0.0f;
    int   nrep = 0;
    if (lane < KADJ) {
        int zz  = lane / 25;
        int rem = lane % 25;
        int dy  = rem / 5 - 2;
        int dx  = rem % 5 - 2;
        int ny = cy + dy, nx = cx + dx;
        if (ny >= 0 && ny < GYD && nx >= 0 && nx < GXD) {
            int nvid = ((b * GZD + zz) * GYD + ny) * GXD + nx;
            float c = cnt[nvid];
            if (c > 0.0f) {
                occ  = true;
                ncn  = fmaxf(c, 1.0f);          // ref: sums / maximum(cnt,1)
                nxc  = sx[nvid] / ncn;
                nyc  = sy[nvid] / ncn;
                nrep = NPTS - 1 - rep[nvid];    // min point index of that voxel
            }
        }
    }

    // own voxel center broadcast from the (dx=0,dy=0,zz=cz) lane
    int lane_own = cz * 25 + 12;
    float cxf    = __shfl(nxc, lane_own);
    float cyf    = __shfl(nyc, lane_own);
    float cn_own = __shfl(ncn, lane_own);

    if (occ) {
        float ddx = cxf - nxc;
        float ddy = cyf - nyc;
        // separate roundings like ref (no FMA contraction)
        float sq = __fadd_rn(__fmul_rn(ddx, ddx), __fmul_rn(ddy, ddy));
        if (sqrtf(sq) < 0.6f && nrep != i)
            unite(parent, i, nrep);
    }

    if (lane == 0) {
        // float32 outputs: cluster_inds interleaved [b,c], valid, cpp
        out[2 * i]                = (float)b;
        out[2 * NPTS + i]         = 1.0f;          // cnt >= MIN_POINTS=1 always
        out[3 * NPTS + 3 * i + 0] = cxf;
        out[3 * NPTS + 3 * i + 1] = cyf;
        out[3 * NPTS + 3 * i + 2] = sz[vid] / cn_own;
    }
}

// Phase 3: labels = component root (== min point index). Separate kernel so all
// unions are device-visible; atomic reads for cross-XCD freshness.
__global__ void k_final(int* parent, float* __restrict__ out) {
    int i = blockIdx.x * blockDim.x + threadIdx.x;
    if (i >= NPTS) return;
    int r = atomicAdd(&parent[i], 0);
    for (;;) {
        int rr = atomicAdd(&parent[r], 0);
        if (rr == r) break;
        r = rr;
    }
    out[2 * i + 1] = (float)r;
}

extern "C" void kernel_launch(void* const* d_in, const int* in_sizes, int n_in,
                              void* d_out, int out_size, void* d_ws, size_t ws_size,
                              hipStream_t stream) {
    const float* pts  = (const float*)d_in[0];
    const int*   bidx = (const int*)d_in[1];
    float* out = (float*)d_out;

    char* w = (char*)d_ws;
    float* cnt    = (float*)(w + 0L * NVP * 4);
    float* sx     = (float*)(w + 1L * NVP * 4);
    float* sy     = (float*)(w + 2L * NVP * 4);
    float* sz     = (float*)(w + 3L * NVP * 4);
    int*   rep    = (int*)  (w + 4L * NVP * 4);
    int*   parent = (int*)  (w + 5L * NVP * 4);   // 8192 ints (init in k_accum)
    // ws use ~9 MB

    // Zero the five dense voxel arrays (cnt/sx/sy/sz/rep).
    hipMemsetAsync(w, 0, 5L * NVP * 4, stream);

    hipLaunchKernelGGL(k_accum, dim3(NPTS / 256), dim3(256), 0, stream,
                       pts, bidx, cnt, sx, sy, sz, rep, parent);
    hipLaunchKernelGGL(k_gather_union, dim3(NPTS * 64 / 256), dim3(256), 0, stream,
                       pts, bidx, cnt, sx, sy, sz, rep, parent, out);
    hipLaunchKernelGGL(k_final, dim3(NPTS / 256), dim3(256), 0, stream,
                       parent, out);
}